// Round 12
// baseline (77.667 us; speedup 1.0000x reference)
//
#include <hip/hip_runtime.h>
#include <math.h>

#define NBATCH 4
#define NPTS   8192
#define KNN    8
#define NCH    4096
#define SLICES 16
#define SLEN   512               // candidates per slice-wave
#define NWIN   8                 // windows per slice
#define WLEN   64                // candidates per window
#define CTR_OFF 64
#define PB_OFF 256
#define C2_OFF (PB_OFF + NBATCH * NPTS * 16)   // after 512KB pair buffer
#define NAUX   82                // 48 recon + 2 percep + 32 bnd blocks

typedef float v2f __attribute__((ext_vector_type(2)));

__device__ __forceinline__ unsigned umin32(unsigned a, unsigned b) { return a < b ? a : b; }

// single-block insert: 8 instrs, bd pinned via tied "+v", in-place descending
// order reads only pre-block values => depth-1 sorted insert (ascending top-8).
// Used ONLY in the merge phases (not the hot scan loop).
#define INSERT8(bd, key)                                          \
    asm("v_med3_u32 %7, %8, %6, %7\n\t"                           \
        "v_med3_u32 %6, %8, %5, %6\n\t"                           \
        "v_med3_u32 %5, %8, %4, %5\n\t"                           \
        "v_med3_u32 %4, %8, %3, %4\n\t"                           \
        "v_med3_u32 %3, %8, %2, %3\n\t"                           \
        "v_med3_u32 %2, %8, %1, %2\n\t"                           \
        "v_med3_u32 %1, %8, %0, %1\n\t"                           \
        "v_min_u32  %0, %0, %8"                                   \
        : "+v"(bd[0]), "+v"(bd[1]), "+v"(bd[2]), "+v"(bd[3]),     \
          "+v"(bd[4]), "+v"(bd[5]), "+v"(bd[6]), "+v"(bd[7])      \
        : "v"(key))

// points (float3) -> pair-interleaved {x0,x1,y0,y1,z0,z1,|p0|^2,|p1|^2};
// tasks [0,16384) = pred pairs, [16384,18432) = chunk2 pairs; zeroes acc + ctr.
__global__ __launch_bounds__(256) void prep_kernel(const float* __restrict__ pts,
                                                   const float* __restrict__ c2,
                                                   float* __restrict__ pb,
                                                   float* __restrict__ c2p,
                                                   double* __restrict__ acc,
                                                   unsigned* __restrict__ ctr) {
    const int gi = blockIdx.x * 256 + threadIdx.x;
    if (gi < 8) acc[gi] = 0.0;
    if (gi == 8) *ctr = 0u;
    const float* src;
    float* dst;
    int pi;
    if (gi < NBATCH * NPTS / 2) { src = pts; dst = pb; pi = gi; }
    else { src = c2; dst = c2p; pi = gi - NBATCH * NPTS / 2; }
    const float2 u0 = *reinterpret_cast<const float2*>(src + (size_t)pi * 6 + 0);
    const float2 u1 = *reinterpret_cast<const float2*>(src + (size_t)pi * 6 + 2);
    const float2 u2 = *reinterpret_cast<const float2*>(src + (size_t)pi * 6 + 4);
    const float x0 = u0.x, y0 = u0.y, z0 = u1.x;
    const float x1 = u1.y, y1 = u2.x, z1 = u2.y;
    float4* o = reinterpret_cast<float4*>(dst + (size_t)pi * 8);
    o[0] = make_float4(x0, x1, y0, y1);
    o[1] = make_float4(z0, z1, x0 * x0 + y0 * y0 + z0 * z0,
                               x1 * x1 + y1 * y1 + z1 * z1);
}

// Continuity kNN, window-min + G=2 query sharing: block = 16 slice-waves x 128
// queries (2 lane-groups A/B). Each wave streams its 512-candidate slice ONCE
// (wave-uniform s_loads, plain C) and evaluates BOTH query sets per pair ->
// scalar traffic per unit work halved. Window minima (26-bit d2|6-bit idx) per
// group; exact med3 top-8 merge per group (stage1 waves 0-3/A,4-7/B; stage2
// waves 0/1), self filtered by index.
__global__ __launch_bounds__(1024, 4) void cont_kernel(const float* __restrict__ pb,
                                                       double* __restrict__ acc) {
    __shared__ unsigned mrg[2][SLICES][KNN][64];   // 64 KB
    const int t    = threadIdx.x;
    const int lane = t & 63;
    const int w    = __builtin_amdgcn_readfirstlane(t >> 6);   // slice id (SGPR)
    const int nqg  = NPTS / 128;                // 64 query-pair-groups per batch
    const int b    = blockIdx.x / nqg;
    const int q0   = (blockIdx.x % nqg) * 128;
    const float* __restrict__ B = pb + (size_t)b * NPTS * 4;

    const int qiA = q0 + lane;
    const int qiB = qiA + 64;
    const float* qpA = B + (size_t)(qiA >> 1) * 8;
    const float* qpB = B + (size_t)(qiB >> 1) * 8;
    const int eA = qiA & 1, eB = qiB & 1;
    const float qxA = qpA[0 + eA], qyA = qpA[2 + eA], qzA = qpA[4 + eA], qwA = qpA[6 + eA];
    const float qxB = qpB[0 + eB], qyB = qpB[2 + eB], qzB = qpB[4 + eB], qwB = qpB[6 + eB];
    const v2f qnpA = {qwA + 1e-6f, qwA + 1e-6f};
    const v2f m2xA = {-2.f * qxA, -2.f * qxA};
    const v2f m2yA = {-2.f * qyA, -2.f * qyA};
    const v2f m2zA = {-2.f * qzA, -2.f * qzA};
    const v2f qnpB = {qwB + 1e-6f, qwB + 1e-6f};
    const v2f m2xB = {-2.f * qxB, -2.f * qxB};
    const v2f m2yB = {-2.f * qyB, -2.f * qyB};
    const v2f m2zB = {-2.f * qzB, -2.f * qzB};

    const float* __restrict__ Sp = B + (size_t)w * SLEN * 4;
    const unsigned jb = (unsigned)(w * SLEN);
    unsigned keyA[NWIN], keyB[NWIN];

#pragma unroll
    for (int wi = 0; wi < NWIN; ++wi) {
        const float* __restrict__ Wp = Sp + wi * (WLEN * 4);
        unsigned wmA0 = 0xFFFFFFFFu, wmA1 = 0xFFFFFFFFu;
        unsigned wmB0 = 0xFFFFFFFFu, wmB1 = 0xFFFFFFFFu;
#pragma unroll
        for (int j = 0; j < WLEN / 2; ++j) {
            const float4 ab = *reinterpret_cast<const float4*>(Wp + j * 8);      // x0 x1 y0 y1
            const float4 cd = *reinterpret_cast<const float4*>(Wp + j * 8 + 4);  // z0 z1 w0 w1
            const v2f xp = {ab.x, ab.y}, yp = {ab.z, ab.w};
            const v2f zp = {cd.x, cd.y}, wp = {cd.z, cd.w};
            v2f sA = wp + qnpA;
            sA = __builtin_elementwise_fma(zp, m2zA, sA);
            sA = __builtin_elementwise_fma(yp, m2yA, sA);
            sA = __builtin_elementwise_fma(xp, m2xA, sA);
            v2f sB = wp + qnpB;
            sB = __builtin_elementwise_fma(zp, m2zB, sB);
            sB = __builtin_elementwise_fma(yp, m2yB, sB);
            sB = __builtin_elementwise_fma(xp, m2xB, sB);
            wmA0 = umin32(wmA0, (__float_as_uint(sA.x) & 0xFFFFFFC0u) | (unsigned)(2 * j));
            wmA1 = umin32(wmA1, (__float_as_uint(sA.y) & 0xFFFFFFC0u) | (unsigned)(2 * j + 1));
            wmB0 = umin32(wmB0, (__float_as_uint(sB.x) & 0xFFFFFFC0u) | (unsigned)(2 * j));
            wmB1 = umin32(wmB1, (__float_as_uint(sB.y) & 0xFFFFFFC0u) | (unsigned)(2 * j + 1));
        }
        const unsigned base = jb + (unsigned)(wi * WLEN);   // scalar per window
        const unsigned wmA = umin32(wmA0, wmA1);
        const unsigned wmB = umin32(wmB0, wmB1);
        keyA[wi] = (wmA & 0xFFFFE000u) | base | (wmA & 63u);
        keyB[wi] = (wmB & 0xFFFFE000u) | base | (wmB & 63u);
    }

#pragma unroll
    for (int wi = 0; wi < NWIN; ++wi) {
        mrg[0][w][wi][lane] = keyA[wi];
        mrg[1][w][wi][lane] = keyB[wi];
    }
    __syncthreads();

    // stage 1: waves 0-3 merge group A (4 slices each), waves 4-7 group B
    if (w < 8) {
        const int g  = w >> 2;
        const int ws = w & 3;
        const unsigned selfidx = (unsigned)(q0 + (g << 6) + lane);
        unsigned best[KNN];
#pragma unroll
        for (int s = 0; s < KNN; ++s) best[s] = 0xFFFFFFFFu;
        for (int sl = 4 * ws; sl < 4 * ws + 4; ++sl) {
#pragma unroll
            for (int u = 0; u < KNN; ++u) {
                unsigned key = mrg[g][sl][u][lane];
                key = ((key & 0x1FFFu) == selfidx) ? 0xFFFFFFFFu : key;
                INSERT8(best, key);
            }
        }
#pragma unroll
        for (int s = 0; s < KNN; ++s) mrg[g][4 * ws][s][lane] = best[s];
    }
    __syncthreads();

    // stage 2: wave 0 -> group A, wave 1 -> group B; closed-form deviation sum
    if (w < 2) {
        const int g = w;
        unsigned best[KNN];
#pragma unroll
        for (int s = 0; s < KNN; ++s) best[s] = 0xFFFFFFFFu;
        for (int gg = 0; gg < 4; ++gg) {
#pragma unroll
            for (int u = 0; u < KNN; ++u) {
                const unsigned key = mrg[g][4 * gg][u][lane];
                INSERT8(best, key);
            }
        }
        float sx = 0.f, sy = 0.f, sz = 0.f, sw = 0.f;
#pragma unroll
        for (int s = 0; s < KNN; ++s) {
            const unsigned n = best[s] & 0x1FFFu;
            const float* np = B + (size_t)(n >> 1) * 8 + (n & 1);
            sx += np[0]; sy += np[2]; sz += np[4]; sw += np[6];
        }
        float ssum = sw - (sx * sx + sy * sy + sz * sz) * (1.f / KNN);
#pragma unroll
        for (int o = 32; o > 0; o >>= 1) ssum += __shfl_down(ssum, o, 64);
        if (lane == 0) atomicAdd(&acc[2], (double)ssum);
    }
}

// Fused aux (512 thr, 82 blocks): [0,48) recon MSE (float4), [48,50) percep
// (float4), [50,82) boundary with G=2: 128 queries/block, 8 waves scan their
// 256 c2-pairs once for both query groups. Last finishing block computes the
// final 5 outputs (counter + threadfence + device-scope atomic reads).
__global__ __launch_bounds__(512) void aux_kernel(const float* __restrict__ a,
                                                  const float* __restrict__ bt,
                                                  const float* __restrict__ a2,
                                                  const float* __restrict__ b2,
                                                  const float* __restrict__ c1,
                                                  const float* __restrict__ c2p,
                                                  double* __restrict__ acc,
                                                  unsigned* __restrict__ ctr,
                                                  float* __restrict__ out) {
    __shared__ float smem[2 * 8 * 64];
    const int t = threadIdx.x;
    const int blk = blockIdx.x;
    if (blk < 50) {
        float s;
        int which;
        if (blk < 48) {
            which = 0;
            const int i = blk * 512 + t;
            const float4 va = reinterpret_cast<const float4*>(a)[i];
            const float4 vb = reinterpret_cast<const float4*>(bt)[i];
            const float dx = va.x - vb.x, dy = va.y - vb.y;
            const float dz = va.z - vb.z, dw = va.w - vb.w;
            s = dx * dx + dy * dy + dz * dz + dw * dw;
        } else {
            which = 1;
            const int i = (blk - 48) * 512 + t;
            const float4 va = reinterpret_cast<const float4*>(a2)[i];
            const float4 vb = reinterpret_cast<const float4*>(b2)[i];
            const float dx = va.x - vb.x, dy = va.y - vb.y;
            const float dz = va.z - vb.z, dw = va.w - vb.w;
            s = dx * dx + dy * dy + dz * dz + dw * dw;
        }
#pragma unroll
        for (int o = 32; o > 0; o >>= 1) s += __shfl_down(s, o, 64);
        if ((t & 63) == 0) smem[t >> 6] = s;
        __syncthreads();
        if (t == 0) {
            float bs = 0.f;
#pragma unroll
            for (int i = 0; i < 8; ++i) bs += smem[i];
            atomicAdd(&acc[which], (double)bs);
        }
    } else {
        const int lane = t & 63;
        const int w8 = __builtin_amdgcn_readfirstlane(t >> 6);   // 0..7
        const int qA = (blk - 50) * 128 + lane;
        const int qB = qA + 64;
        const float qxA = c1[qA * 3 + 0], qyA = c1[qA * 3 + 1], qzA = c1[qA * 3 + 2];
        const float qxB = c1[qB * 3 + 0], qyB = c1[qB * 3 + 1], qzB = c1[qB * 3 + 2];
        const float qnA = qxA * qxA + qyA * qyA + qzA * qzA;
        const float qnB = qxB * qxB + qyB * qyB + qzB * qzB;
        const v2f m2xA = {-2.f * qxA, -2.f * qxA};
        const v2f m2yA = {-2.f * qyA, -2.f * qyA};
        const v2f m2zA = {-2.f * qzA, -2.f * qzA};
        const v2f m2xB = {-2.f * qxB, -2.f * qxB};
        const v2f m2yB = {-2.f * qyB, -2.f * qyB};
        const v2f m2zB = {-2.f * qzB, -2.f * qzB};
        float mA = 3.0e38f, mB = 3.0e38f;
        const float* __restrict__ Sp = c2p + (size_t)w8 * 256 * 8;   // 256 pairs
#pragma unroll 8
        for (int j = 0; j < 256; ++j) {
            const float4 ab = *reinterpret_cast<const float4*>(Sp + j * 8);
            const float4 cd = *reinterpret_cast<const float4*>(Sp + j * 8 + 4);
            const v2f xp = {ab.x, ab.y}, yp = {ab.z, ab.w};
            const v2f zp = {cd.x, cd.y}, wp = {cd.z, cd.w};
            v2f sA = wp;
            sA = __builtin_elementwise_fma(zp, m2zA, sA);
            sA = __builtin_elementwise_fma(yp, m2yA, sA);
            sA = __builtin_elementwise_fma(xp, m2xA, sA);
            v2f sB = wp;
            sB = __builtin_elementwise_fma(zp, m2zB, sB);
            sB = __builtin_elementwise_fma(yp, m2yB, sB);
            sB = __builtin_elementwise_fma(xp, m2xB, sB);
            mA = fminf(mA, fminf(sA.x, sA.y));
            mB = fminf(mB, fminf(sB.x, sB.y));
        }
        smem[0 * 512 + w8 * 64 + lane] = mA;
        smem[1 * 512 + w8 * 64 + lane] = mB;
        __syncthreads();
        if (w8 < 2) {
            const float qn = (w8 == 0) ? qnA : qnB;
            float mm = smem[w8 * 512 + lane];
#pragma unroll
            for (int s = 1; s < 8; ++s) mm = fminf(mm, smem[w8 * 512 + s * 64 + lane]);
            const float d = sqrtf(fmaxf(mm + qn, 0.f));
            const bool in = d < 0.1f;
            float sc = in ? d : 0.f;
            float sn = in ? 1.f : 0.f;
#pragma unroll
            for (int o = 32; o > 0; o >>= 1) {
                sc += __shfl_down(sc, o, 64);
                sn += __shfl_down(sn, o, 64);
            }
            if (lane == 0) {
                atomicAdd(&acc[3], (double)sc);
                atomicAdd(&acc[4], (double)sn);
            }
        }
    }
    // last-done block finalizes the 5 outputs
    __syncthreads();
    if (t == 0) {
        __threadfence();
        const unsigned old = atomicAdd(ctr, 1u);
        if (old == NAUX - 1) {
            __threadfence();
            const double a0 = atomicAdd(&acc[0], 0.0);
            const double a1 = atomicAdd(&acc[1], 0.0);
            const double a2d = atomicAdd(&acc[2], 0.0);
            const double a3 = atomicAdd(&acc[3], 0.0);
            const double a4 = atomicAdd(&acc[4], 0.0);
            const double recon  = a0 / (double)(NBATCH * NPTS * 3);
            const double percep = a1 / 4096.0;
            const double cont   = a2d / (double)(NBATCH * NPTS * KNN);
            const double bnd    = (a4 > 0.0) ? a3 / ((a4 > 1.0) ? a4 : 1.0) : 0.0;
            const double total  = recon + 0.5 * percep + 0.5 * cont + bnd;
            out[0] = (float)recon;
            out[1] = (float)percep;
            out[2] = (float)cont;
            out[3] = (float)bnd;
            out[4] = (float)total;
        }
    }
}

extern "C" void kernel_launch(void* const* d_in, const int* in_sizes, int n_in,
                              void* d_out, int out_size, void* d_ws, size_t ws_size,
                              hipStream_t stream) {
    const float* pred = (const float*)d_in[0];
    const float* targ = (const float*)d_in[1];
    const float* pf   = (const float*)d_in[2];
    const float* tf   = (const float*)d_in[3];
    const float* c1   = (const float*)d_in[4];
    const float* c2   = (const float*)d_in[5];
    float* out  = (float*)d_out;
    double* acc = (double*)d_ws;
    unsigned* ctr = (unsigned*)((char*)d_ws + CTR_OFF);
    float* pb   = (float*)((char*)d_ws + PB_OFF);
    float* c2p  = (float*)((char*)d_ws + C2_OFF);

    hipLaunchKernelGGL(prep_kernel, dim3((NBATCH * NPTS / 2 + NCH / 2) / 256), dim3(256),
                       0, stream, pred, c2, pb, c2p, acc, ctr);
    hipLaunchKernelGGL(cont_kernel, dim3(NBATCH * (NPTS / 128)), dim3(1024), 0, stream,
                       pb, acc);
    hipLaunchKernelGGL(aux_kernel, dim3(NAUX), dim3(512), 0, stream,
                       pred, targ, pf, tf, c1, c2p, acc, ctr, out);
}

// Round 13
// 71.243 us; speedup vs baseline: 1.0902x; 1.0902x over previous
//
#include <hip/hip_runtime.h>
#include <math.h>

#define NBATCH 4
#define NPTS   8192
#define KNN    8
#define NCH    4096
#define SLICES 16
#define SLEN   512               // candidates per slice-wave
#define NWIN   8                 // windows per slice
#define WLEN   64                // candidates per window
#define CTR_OFF 64
#define PB_OFF  256                                  // f16 pair buffer (12B/pair)
#define C2_OFF  (PB_OFF + NBATCH * (NPTS / 2) * 12)  // f32 c2 pair buffer
#define NAUX   114               // 48 recon + 2 percep + 64 bnd blocks

typedef float    v2f __attribute__((ext_vector_type(2)));
typedef _Float16 v2h __attribute__((ext_vector_type(2)));

__device__ __forceinline__ unsigned umin32(unsigned a, unsigned b) { return a < b ? a : b; }
__device__ __forceinline__ unsigned h2u(v2h v) { unsigned u; __builtin_memcpy(&u, &v, 4); return u; }
__device__ __forceinline__ v2h u2h(unsigned u) { v2h v; __builtin_memcpy(&v, &u, 4); return v; }

// single-block insert: 8 instrs, bd pinned via tied "+v", in-place descending
// order reads only pre-block values => depth-1 sorted insert (ascending top-8).
// Used ONLY in the merge phases (not the hot scan loop).
#define INSERT8(bd, key)                                          \
    asm("v_med3_u32 %7, %8, %6, %7\n\t"                           \
        "v_med3_u32 %6, %8, %5, %6\n\t"                           \
        "v_med3_u32 %5, %8, %4, %5\n\t"                           \
        "v_med3_u32 %4, %8, %3, %4\n\t"                           \
        "v_med3_u32 %3, %8, %2, %3\n\t"                           \
        "v_med3_u32 %2, %8, %1, %2\n\t"                           \
        "v_med3_u32 %1, %8, %0, %1\n\t"                           \
        "v_min_u32  %0, %0, %8"                                   \
        : "+v"(bd[0]), "+v"(bd[1]), "+v"(bd[2]), "+v"(bd[3]),     \
          "+v"(bd[4]), "+v"(bd[5]), "+v"(bd[6]), "+v"(bd[7])      \
        : "v"(key))

// pred pairs -> packed f16 {x0x1,y0y1,z0z1} (12B); c2 pairs -> f32 pair buffer;
// zeroes acc + ctr.
__global__ __launch_bounds__(256) void prep_kernel(const float* __restrict__ pts,
                                                   const float* __restrict__ c2,
                                                   unsigned* __restrict__ pb16,
                                                   float* __restrict__ c2p,
                                                   double* __restrict__ acc,
                                                   unsigned* __restrict__ ctr) {
    const int gi = blockIdx.x * 256 + threadIdx.x;
    if (gi < 8) acc[gi] = 0.0;
    if (gi == 8) *ctr = 0u;
    if (gi < NBATCH * NPTS / 2) {
        const float* s = pts + (size_t)gi * 6;
        const v2h xp = {(_Float16)s[0], (_Float16)s[3]};
        const v2h yp = {(_Float16)s[1], (_Float16)s[4]};
        const v2h zp = {(_Float16)s[2], (_Float16)s[5]};
        pb16[gi * 3 + 0] = h2u(xp);
        pb16[gi * 3 + 1] = h2u(yp);
        pb16[gi * 3 + 2] = h2u(zp);
    } else {
        const int pi = gi - NBATCH * NPTS / 2;      // 0..2047
        const float* s = c2 + (size_t)pi * 6;
        const float x0 = s[0], y0 = s[1], z0 = s[2];
        const float x1 = s[3], y1 = s[4], z1 = s[5];
        float4* o = reinterpret_cast<float4*>(c2p + (size_t)pi * 8);
        o[0] = make_float4(x0, x1, y0, y1);
        o[1] = make_float4(z0, z1, x0 * x0 + y0 * y0 + z0 * z0,
                                   x1 * x1 + y1 * y1 + z1 * z1);
    }
}

// Continuity kNN, window-min + f16 stream: block = 16 slice-waves; every wave
// holds the SAME 64 queries (one per lane), scans its 512-candidate slice as 8
// windows of 64 via wave-uniform s_loads of packed-f16 pairs (12B/pair — 2.7x
// deeper load pipeline per SGPR than f32). Distance in f16 difference form
// (pk_sub/mul/fma, no cancellation). Window min key = f16 d2 bits[31:16] |
// local idx[5:0]; re-packed to global idx[12:0]; exact med3 top-8 merge, self
// (d2==+0, key==idx) filtered by index. Deviation gather from f32 pred.
__global__ __launch_bounds__(1024, 8) void cont_kernel(const unsigned* __restrict__ pb16,
                                                       const float* __restrict__ pred,
                                                       double* __restrict__ acc) {
    __shared__ unsigned mrg[SLICES][KNN][64];   // 32 KB, lane-consecutive
    const int t    = threadIdx.x;
    const int lane = t & 63;
    const int w    = __builtin_amdgcn_readfirstlane(t >> 6);   // slice id (SGPR)
    const int nqw  = NPTS / 64;
    const int b    = blockIdx.x / nqw;
    const int q0   = (blockIdx.x % nqw) * 64;
    const unsigned* __restrict__ B = pb16 + (size_t)b * (NPTS / 2) * 3;

    const int qi = q0 + lane;
    const unsigned* qp = B + (size_t)(qi >> 1) * 3;
    const int e = qi & 1;
    const v2h xqv = u2h(qp[0]), yqv = u2h(qp[1]), zqv = u2h(qp[2]);
    const _Float16 qxh = xqv[e], qyh = yqv[e], qzh = zqv[e];
    const v2h qx2 = {qxh, qxh}, qy2 = {qyh, qyh}, qz2 = {qzh, qzh};

    const unsigned* __restrict__ Sp = B + (size_t)w * (SLEN / 2) * 3;
    const unsigned jb = (unsigned)(w * SLEN);
    unsigned keyout[NWIN];

#pragma unroll
    for (int wi = 0; wi < NWIN; ++wi) {
        const unsigned* __restrict__ Wp = Sp + wi * ((WLEN / 2) * 3);
        unsigned wmA = 0xFFFFFFFFu, wmB = 0xFFFFFFFFu;
#pragma unroll
        for (int j = 0; j < WLEN / 2; ++j) {
            const v2h xh = u2h(Wp[j * 3 + 0]);
            const v2h yh = u2h(Wp[j * 3 + 1]);
            const v2h zh = u2h(Wp[j * 3 + 2]);
            const v2h dx = xh - qx2;
            const v2h dy = yh - qy2;
            const v2h dz = zh - qz2;
            v2h d2 = dx * dx;
            d2 = __builtin_elementwise_fma(dy, dy, d2);
            d2 = __builtin_elementwise_fma(dz, dz, d2);
            const unsigned bits = h2u(d2);
            const unsigned k0 = (bits << 16) | (unsigned)(2 * j);        // lo cand
            const unsigned k1 = (bits & 0xFFFF0000u) | (unsigned)(2 * j + 1); // hi
            wmA = umin32(wmA, k0);
            wmB = umin32(wmB, k1);
        }
        const unsigned wm = umin32(wmA, wmB);
        keyout[wi] = (wm & 0xFFFF0000u) | (jb + (unsigned)(wi * WLEN)) | (wm & 63u);
    }

#pragma unroll
    for (int wi = 0; wi < NWIN; ++wi) mrg[w][wi][lane] = keyout[wi];
    __syncthreads();

    // stage 1: waves 0..3 each merge 4 slices' window minima (self filtered)
    if (w < 4) {
        const unsigned selfidx = (unsigned)qi;
        unsigned best[KNN];
#pragma unroll
        for (int s = 0; s < KNN; ++s) best[s] = 0xFFFFFFFFu;
        for (int sl = 4 * w; sl < 4 * w + 4; ++sl) {
#pragma unroll
            for (int u = 0; u < KNN; ++u) {
                unsigned key = mrg[sl][u][lane];
                key = ((key & 0x1FFFu) == selfidx) ? 0xFFFFFFFFu : key;
                INSERT8(best, key);
            }
        }
#pragma unroll
        for (int s = 0; s < KNN; ++s) mrg[4 * w][s][lane] = best[s];
    }
    __syncthreads();

    // stage 2: wave 0 merges the 4 partials; deviation sum from f32 pred
    if (w == 0) {
        unsigned best[KNN];
#pragma unroll
        for (int s = 0; s < KNN; ++s) best[s] = 0xFFFFFFFFu;
        for (int g = 0; g < 4; ++g) {
#pragma unroll
            for (int u = 0; u < KNN; ++u) {
                const unsigned key = mrg[4 * g][u][lane];
                INSERT8(best, key);
            }
        }
        const float* __restrict__ P = pred + (size_t)b * NPTS * 3;
        float sx = 0.f, sy = 0.f, sz = 0.f, sw = 0.f;
#pragma unroll
        for (int s = 0; s < KNN; ++s) {
            const unsigned n = best[s] & 0x1FFFu;
            const float* np = P + (size_t)n * 3;
            const float x = np[0], y = np[1], z = np[2];
            sx += x; sy += y; sz += z;
            sw += x * x + y * y + z * z;
        }
        float ssum = sw - (sx * sx + sy * sy + sz * sz) * (1.f / KNN);
#pragma unroll
        for (int o = 32; o > 0; o >>= 1) ssum += __shfl_down(ssum, o, 64);
        if (lane == 0) atomicAdd(&acc[2], (double)ssum);
    }
}

// Fused aux (512 thr, 114 blocks): [0,48) recon MSE (float4), [48,50) percep
// (float4), [50,114) boundary G=1: 64 queries/block, 8 waves x 256 f32 c2-pairs
// via wave-uniform s_loads + packed min of |p|^2-2p.q; |q|^2 added once.
// Last finishing block computes the final 5 outputs.
__global__ __launch_bounds__(512) void aux_kernel(const float* __restrict__ a,
                                                  const float* __restrict__ bt,
                                                  const float* __restrict__ a2,
                                                  const float* __restrict__ b2,
                                                  const float* __restrict__ c1,
                                                  const float* __restrict__ c2p,
                                                  double* __restrict__ acc,
                                                  unsigned* __restrict__ ctr,
                                                  float* __restrict__ out) {
    __shared__ float smem[8 * 64];
    const int t = threadIdx.x;
    const int blk = blockIdx.x;
    if (blk < 50) {
        float s;
        int which;
        if (blk < 48) {
            which = 0;
            const int i = blk * 512 + t;
            const float4 va = reinterpret_cast<const float4*>(a)[i];
            const float4 vb = reinterpret_cast<const float4*>(bt)[i];
            const float dx = va.x - vb.x, dy = va.y - vb.y;
            const float dz = va.z - vb.z, dw = va.w - vb.w;
            s = dx * dx + dy * dy + dz * dz + dw * dw;
        } else {
            which = 1;
            const int i = (blk - 48) * 512 + t;
            const float4 va = reinterpret_cast<const float4*>(a2)[i];
            const float4 vb = reinterpret_cast<const float4*>(b2)[i];
            const float dx = va.x - vb.x, dy = va.y - vb.y;
            const float dz = va.z - vb.z, dw = va.w - vb.w;
            s = dx * dx + dy * dy + dz * dz + dw * dw;
        }
#pragma unroll
        for (int o = 32; o > 0; o >>= 1) s += __shfl_down(s, o, 64);
        if ((t & 63) == 0) smem[t >> 6] = s;
        __syncthreads();
        if (t == 0) {
            float bs = 0.f;
#pragma unroll
            for (int i = 0; i < 8; ++i) bs += smem[i];
            atomicAdd(&acc[which], (double)bs);
        }
    } else {
        const int lane = t & 63;
        const int w8 = __builtin_amdgcn_readfirstlane(t >> 6);   // 0..7
        const int qi = (blk - 50) * 64 + lane;
        const float qx = c1[qi * 3 + 0];
        const float qy = c1[qi * 3 + 1];
        const float qz = c1[qi * 3 + 2];
        const float qn = qx * qx + qy * qy + qz * qz;
        const v2f m2x2 = {-2.f * qx, -2.f * qx};
        const v2f m2y2 = {-2.f * qy, -2.f * qy};
        const v2f m2z2 = {-2.f * qz, -2.f * qz};
        float m = 3.0e38f;
        const float* __restrict__ Sp = c2p + (size_t)w8 * 256 * 8;   // 256 pairs
#pragma unroll 16
        for (int j = 0; j < 256; ++j) {
            const float4 ab = *reinterpret_cast<const float4*>(Sp + j * 8);
            const float4 cd = *reinterpret_cast<const float4*>(Sp + j * 8 + 4);
            const v2f xp = {ab.x, ab.y}, yp = {ab.z, ab.w};
            const v2f zp = {cd.x, cd.y};
            v2f s2 = {cd.z, cd.w};
            s2 = __builtin_elementwise_fma(zp, m2z2, s2);
            s2 = __builtin_elementwise_fma(yp, m2y2, s2);
            s2 = __builtin_elementwise_fma(xp, m2x2, s2);
            m = fminf(m, fminf(s2.x, s2.y));
        }
        smem[w8 * 64 + lane] = m;
        __syncthreads();
        if (w8 == 0) {
            float mm = smem[lane];
#pragma unroll
            for (int s = 1; s < 8; ++s) mm = fminf(mm, smem[s * 64 + lane]);
            const float d = sqrtf(fmaxf(mm + qn, 0.f));
            const bool in = d < 0.1f;
            float sc = in ? d : 0.f;
            float sn = in ? 1.f : 0.f;
#pragma unroll
            for (int o = 32; o > 0; o >>= 1) {
                sc += __shfl_down(sc, o, 64);
                sn += __shfl_down(sn, o, 64);
            }
            if (lane == 0) {
                atomicAdd(&acc[3], (double)sc);
                atomicAdd(&acc[4], (double)sn);
            }
        }
    }
    // last-done block finalizes the 5 outputs
    __syncthreads();
    if (t == 0) {
        __threadfence();
        const unsigned old = atomicAdd(ctr, 1u);
        if (old == NAUX - 1) {
            __threadfence();
            const double a0 = atomicAdd(&acc[0], 0.0);
            const double a1 = atomicAdd(&acc[1], 0.0);
            const double a2d = atomicAdd(&acc[2], 0.0);
            const double a3 = atomicAdd(&acc[3], 0.0);
            const double a4 = atomicAdd(&acc[4], 0.0);
            const double recon  = a0 / (double)(NBATCH * NPTS * 3);
            const double percep = a1 / 4096.0;
            const double cont   = a2d / (double)(NBATCH * NPTS * KNN);
            const double bnd    = (a4 > 0.0) ? a3 / ((a4 > 1.0) ? a4 : 1.0) : 0.0;
            const double total  = recon + 0.5 * percep + 0.5 * cont + bnd;
            out[0] = (float)recon;
            out[1] = (float)percep;
            out[2] = (float)cont;
            out[3] = (float)bnd;
            out[4] = (float)total;
        }
    }
}

extern "C" void kernel_launch(void* const* d_in, const int* in_sizes, int n_in,
                              void* d_out, int out_size, void* d_ws, size_t ws_size,
                              hipStream_t stream) {
    const float* pred = (const float*)d_in[0];
    const float* targ = (const float*)d_in[1];
    const float* pf   = (const float*)d_in[2];
    const float* tf   = (const float*)d_in[3];
    const float* c1   = (const float*)d_in[4];
    const float* c2   = (const float*)d_in[5];
    float* out  = (float*)d_out;
    double* acc = (double*)d_ws;
    unsigned* ctr = (unsigned*)((char*)d_ws + CTR_OFF);
    unsigned* pb16 = (unsigned*)((char*)d_ws + PB_OFF);
    float* c2p  = (float*)((char*)d_ws + C2_OFF);

    hipLaunchKernelGGL(prep_kernel, dim3((NBATCH * NPTS / 2 + NCH / 2) / 256), dim3(256),
                       0, stream, pred, c2, pb16, c2p, acc, ctr);
    hipLaunchKernelGGL(cont_kernel, dim3(NBATCH * (NPTS / 64)), dim3(1024), 0, stream,
                       pb16, pred, acc);
    hipLaunchKernelGGL(aux_kernel, dim3(NAUX), dim3(512), 0, stream,
                       pred, targ, pf, tf, c1, c2p, acc, ctr, out);
}